// Round 15
// baseline (895.179 us; speedup 1.0000x reference)
//
#include <hip/hip_runtime.h>
#include <hip/hip_bf16.h>
#include <math.h>

using bf16 = __hip_bfloat16;

typedef short s8v __attribute__((ext_vector_type(8)));   // 8 bf16 bit-pattern (4 VGPRs)
typedef float f4v __attribute__((ext_vector_type(4)));   // MFMA accumulator

// ---------------- problem dims ----------------
static constexpr int  BB  = 2048;
static constexpr int  IH  = 23, IW = 31;   // stage 1 spatial
static constexpr int  PH  = 11, PW = 15;   // after pool1
static constexpr int  QH  = 5,  QW = 7;    // after pool2
static constexpr long NSITE1 = (long)BB * IH * IW;   // 1,460,224 = 5704*256
static constexpr long NSITE2 = (long)BB * PH * PW;   //   337,920
static constexpr long NSITE3 = (long)BB * QH * QW;   //    71,680

// ---------------- workspace layout ----------------
static constexpr long OFF_N1 = 640, OFF_N2 = 641;
static constexpr long OFF_M0 = 2048;
static constexpr long OFF_M1 = OFF_M0 + NSITE1;
static constexpr long OFF_M2 = OFF_M1 + NSITE2;      // m2h: hw-major mask [hw*2048+b]
static constexpr long OFF_BF = 1871872;              // float offset where bf16 area starts
static constexpr long SZ_A   = 43253760L;            // bf16 elems per region
static constexpr long WB2_A  = 25000000L;  // [9][32][32]
static constexpr long WB3_B  = 22000000L;  // [9][64][32]
static constexpr long WB4_B  = 22100000L;  // [9][128][64]
static constexpr long WBL_A  = 20000000L;  // [9][4][768][32] = 884,736
static constexpr long WFC1_B = 23000000L;  // wfc1T8 [1120][1024][8] = 9,175,040
static constexpr long WFC2_B = 33000000L;  // wfc2 hi/lo T8 [128][448][8] x2 = 917,504 (ends 33,917,504)
static constexpr long BKT_A  = 40000000L;  // bufA+40M bf16: f32 bkt16|bkt32 (6144 f)
static constexpr long BKT_B  = 34000000L;  // bufB+34M bf16: f32 bkt64|bkt128 (24576 f)
// Bucket lifetime safety (conv4 folds BN3 ITSELF, so bkt64 must survive conv4's writes):
//  bkt16/32 in bufA+40M: written by conv1/conv2 atomics, read by conv2/maxpool_bn folds;
//    bufA>=40M untouched in that window (c1 ends 23.4M; p1 ends 10.8M).
//  bkt64/128 in bufB+34M: written by conv3/conv4 atomics, read by conv4/maxpool_p2t folds;
//    conv4 writes c4 in bufA only; p2T8 ends 18.35M; wfc2 ends 33.92M. No overlap.

__device__ __forceinline__ float b2f(bf16 v) { return __bfloat162float(v); }
__device__ __forceinline__ bf16  f2b(float v) { return __float2bfloat16(v); }
__device__ __forceinline__ float sigmoidf_(float x) {
    return __builtin_amdgcn_rcpf(1.f + __expf(-x));
}
// fast tanh: clamp keeps exp finite; (1-t)/(1+t) with rcp. |err| ~1e-6, fine for bf16 out.
__device__ __forceinline__ float tanhf_(float x) {
    float xc = fminf(fmaxf(x, -15.f), 15.f);
    float t = __expf(-2.f * xc);
    return (1.f - t) * __builtin_amdgcn_rcpf(1.f + t);
}

__device__ __forceinline__ void ld8(const bf16* p, float* f) {
    union { uint4 u; unsigned short s[8]; } cv;
    cv.u = *(const uint4*)p;
#pragma unroll
    for (int i = 0; i < 8; i++) f[i] = __uint_as_float(((unsigned int)cv.s[i]) << 16);
}
__device__ __forceinline__ void st8(bf16* p, const float* f) {
    union { uint4 u; bf16 h[8]; } cv;
#pragma unroll
    for (int i = 0; i < 8; i++) cv.h[i] = f2b(f[i]);
    *(uint4*)p = cv.u;
}

// ---------------- inline weight-cvt body: W[tap][cin][cout] f32 -> wb[tap][cout][cinp] bf16 ----
__device__ __forceinline__ void cvt_w_body(const float* __restrict__ W, bf16* __restrict__ wb,
                                           int CIN, int CINP, int COUT, int total, int idx) {
    if (idx >= total) return;
    int ci  = idx % CINP;
    int t2  = idx / CINP;
    int co  = t2 % COUT;
    int tap = t2 / COUT;
    wb[idx] = (ci < CIN) ? f2b(W[((long)(tap * CIN + ci)) * COUT + co]) : f2b(0.f);
}

// ---------------- prep + W2 cvt merged (independent; saves a launch) ----------------
__global__ void prep_cvtw2_k(const float* __restrict__ x, const int* __restrict__ mask,
                             float* __restrict__ m0, bf16* __restrict__ xm,
                             const float* __restrict__ W2, bf16* __restrict__ wb2) {
    int bid = blockIdx.x, tid = threadIdx.x;
    if (bid < 5704) {                                 // prep: NSITE1 exact
        long idx = (long)bid * 256 + tid;
        float m = (mask[idx] != 0) ? 1.f : 0.f;
        m0[idx] = m;
        xm[idx * 2 + 0] = f2b(x[idx * 2 + 0] * m);
        xm[idx * 2 + 1] = f2b(x[idx * 2 + 1] * m);
    } else {                                          // cvt W2: 9216 elems, 36 blocks
        cvt_w_body(W2, wb2, 16, 32, 32, 9216, (bid - 5704) * 256 + tid);
    }
}

// ---------------- merged weight converts (W3 | W4 | fc1T8 | fc2T8) ----------------
__global__ void cvt_all_k(const float* __restrict__ W3, const float* __restrict__ W4,
                          const float* __restrict__ lw1, const float* __restrict__ lw2,
                          bf16* __restrict__ wb3, bf16* __restrict__ wb4,
                          bf16* __restrict__ wfc1, bf16* __restrict__ whi,
                          bf16* __restrict__ wlo) {
    int bid = blockIdx.x, tid = threadIdx.x;
    if (bid < 72) {                                   // W3: 18432
        cvt_w_body(W3, wb3, 32, 32, 64, 18432, bid * 256 + tid);
    } else if (bid < 360) {                           // W4: 73728
        cvt_w_body(W4, wb4, 64, 64, 128, 73728, (bid - 72) * 256 + tid);
    } else if (bid < 4840) {                          // fc1T8: 1,146,880 exact
        int t = (bid - 360) * 256 + tid;
        int j   = t & 1023;
        int k8g = t >> 10;
        int hw  = k8g >> 5;
        int c8  = k8g & 31;
        float f[8];
#pragma unroll
        for (int c7 = 0; c7 < 8; c7++)
            f[c7] = lw1[((long)((c8 * 8 + c7) * 35 + hw)) * 1024 + j];
        st8(wfc1 + (long)t * 8, f);
    } else {                                          // fc2T8: 57,344 exact (224 blocks)
        int t = (bid - 4840) * 256 + tid;
        int n  = t % 448;
        int k8 = t / 448;
        union { uint4 u; bf16 h8[8]; } h, l;
#pragma unroll
        for (int ki = 0; ki < 8; ki++) {
            float v = (n < 420) ? lw2[(long)(k8 * 8 + ki) * 420 + n] : 0.f;
            bf16 hb = f2b(v);
            h.h8[ki] = hb;
            l.h8[ki] = f2b(v - b2f(hb));
        }
        *(uint4*)(whi + (long)t * 8) = h.u;
        *(uint4*)(wlo + (long)t * 8) = l.u;
    }
}

// ---------------- conv1: 2->16, fused BN1-stats via wave shuffle reduction + N1 count ----------------
__global__ void conv1_k(const bf16* __restrict__ xm, const float* __restrict__ Wt,
                        const float* __restrict__ m0, bf16* __restrict__ out,
                        float* __restrict__ bkt, float* __restrict__ cnt) {
    __shared__ float s_s[16], s_q[16], s_c;
    const int H = IH, W = IW;
    int tid = threadIdx.x;
    int L = tid & 63;
    if (tid < 16) { s_s[tid] = 0.f; s_q[tid] = 0.f; }
    if (tid == 0) s_c = 0.f;
    __syncthreads();
    long site = (long)blockIdx.x * 256 + tid;        // grid exact: NSITE1 = 5704*256
    float acc[16];
#pragma unroll
    for (int i = 0; i < 16; i++) acc[i] = 0.f;
    float mk = 0.f;
    if (site < NSITE1) {
        mk = m0[site];
        if (mk > 0.f) {
            int w = (int)(site % W); int h = (int)((site / W) % H);
            for (int tap = 0; tap < 9; tap++) {
                int dh = tap / 3 - 1, dw = tap % 3 - 1;
                int nh = h + dh, nw = w + dw;
                if (nh < 0 || nh >= H || nw < 0 || nw >= W) continue;
                long ns = site + (long)dh * W + dw;
                float i0 = b2f(xm[ns * 2 + 0]), i1 = b2f(xm[ns * 2 + 1]);
                const float* wp = Wt + tap * 32;
#pragma unroll
                for (int co = 0; co < 16; co++) acc[co] += i0 * wp[co] + i1 * wp[16 + co];
            }
        }
        st8(out + site * 16, acc);
        st8(out + site * 16 + 8, acc + 8);
    }
    // stats on bf16-rounded stored values; wave butterfly then lane0 atomics
#pragma unroll
    for (int i = 0; i < 16; i++) {
        float vb = (site < NSITE1) ? b2f(f2b(acc[i])) : 0.f;
        float s = vb, q2 = vb * vb;
#pragma unroll
        for (int off = 32; off > 0; off >>= 1) {
            s  += __shfl_xor(s, off);
            q2 += __shfl_xor(q2, off);
        }
        if (L == 0) { atomicAdd(&s_s[i], s); atomicAdd(&s_q[i], q2); }
    }
    {
        float c = (mk > 0.f) ? 1.f : 0.f;
#pragma unroll
        for (int off = 32; off > 0; off >>= 1) c += __shfl_xor(c, off);
        if (L == 0) atomicAdd(&s_c, c);
    }
    __syncthreads();
    int bk = blockIdx.x & 63;
    if (tid < 16) {
        atomicAdd(bkt + (long)bk * 32 + tid, s_s[tid]);
        atomicAdd(bkt + (long)bk * 32 + 16 + tid, s_q[tid]);
    }
    if (tid == 0) atomicAdd(cnt, s_c);
}

// ---------------- MFMA direct conv 3x3 SAME, LDS-staged A (b-major sites) ----------------
// BN: fold 64-bucket input stats -> scale/shift IN-BLOCK (bit-identical loop to the old
// bn_param_bkt kernel; removes a 1-block launch bubble), then fuse affine+ReLU+mask into
// staging. STATS: per-channel sum/sumsq of the bf16-rounded output into 64-way buckets,
// cross-q shuffle-folded (round-13/14 lesson: q-aliased LDS atomics = 5.67M conflicts).
template<int CIN, int CINP, int COUT, int KK, int MT_W, int NT_W, int H, int W,
         bool ZPAD, bool BN, bool STATS, bool CNT>
__global__ void conv_mfma(const bf16* __restrict__ in, const bf16* __restrict__ wb,
                          const float* __restrict__ mask,
                          const float* __restrict__ bktIn, const float* __restrict__ cntIn,
                          const float* __restrict__ gIn, const float* __restrict__ bIn,
                          bf16* __restrict__ out,
                          float* __restrict__ bktOut, float* __restrict__ cntOut) {
    constexpr int NT   = COUT / 16;
    constexpr int NWN  = NT / NT_W;
    constexpr int HALO = W + 1;
    constexpr int REG  = 64 + 2 * HALO;     // staged sites
    constexpr int SE   = CIN + 8;           // LDS site stride (elems), +16B pad
    constexpr int CHPS = CIN / 8;           // 16B chunks per site
    __shared__ bf16 smem[(REG + 1) * SE];
    __shared__ float s_s[COUT], s_q[COUT], s_c;
    __shared__ float s_sc[CIN], s_sh[CIN];

    const int tid = threadIdx.x;
    const int wv = tid >> 6;
    const int L  = tid & 63;
    const int q  = (L >> 4);
    const int lm = L & 15;
    const int wn = wv % NWN;
    const int wm = wv / NWN;
    const int mt0 = wm * MT_W;
    const long base = (long)blockIdx.x * 64;
    const long nsites = (long)gridDim.x * 64;

    if (BN) {
        if (tid < CIN) {
            float s = 0.f, q2 = 0.f;
            for (int k = 0; k < 64; k++) {
                s  += bktIn[(long)k * 2 * CIN + tid];
                q2 += bktIn[(long)k * 2 * CIN + CIN + tid];
            }
            float n = fmaxf(cntIn[0], 1.f);
            float mean = s / n;
            float var  = q2 / n - mean * mean;
            float scv = (1.f / sqrtf(var + 1e-4f)) * gIn[tid];
            s_sc[tid] = scv;
            s_sh[tid] = bIn[tid] - mean * scv;
        }
        __syncthreads();
    }

    // ---- stage A halo into LDS (reg-staged; padded stride forbids global_load_lds) ----
    for (int c = tid; c < REG * CHPS; c += 256) {
        int s = c / CHPS;
        int o = c % CHPS;
        long gs = base - HALO + s;
        uint4 v = {0u, 0u, 0u, 0u};
        if (gs >= 0 && gs < nsites) {
            v = *(const uint4*)(in + gs * CIN + o * 8);
            if (BN) {
                float mk = mask[gs];
                union { uint4 u; unsigned short us[8]; } cv; cv.u = v;
                union { uint4 u; bf16 h[8]; } ov;
#pragma unroll
                for (int i = 0; i < 8; i++) {
                    float f = __uint_as_float(((unsigned int)cv.us[i]) << 16);
                    int ch = o * 8 + i;
                    float r = fmaxf(f * s_sc[ch] + s_sh[ch], 0.f);
                    ov.h[i] = f2b(mk > 0.f ? r : 0.f);
                }
                v = ov.u;
            }
        }
        *(uint4*)(smem + s * SE + o * 8) = v;
    }
    if (ZPAD) {
        uint4 z = {0u, 0u, 0u, 0u};
        for (int s = tid; s < REG; s += 256)
            *(uint4*)(smem + s * SE + CIN) = z;              // per-site pad lane
        if (tid == 0)
            *(uint4*)(smem + REG * SE) = z;                  // tail (last site's q=3 over-read)
    }
    if (STATS) {
        if (tid < COUT) { s_s[tid] = 0.f; s_q[tid] = 0.f; }
        if (tid == 0) s_c = 0.f;
    }
    __syncthreads();

    int hh[MT_W], ww[MT_W];
#pragma unroll
    for (int i = 0; i < MT_W; i++) {
        long s = base + (mt0 + i) * 16 + lm;
        ww[i] = (int)(s % W);
        hh[i] = (int)((s / W) % H);
    }
    const int lbase = mt0 * 16 + lm + HALO;   // local site idx of this lane's tile row 0

    f4v acc[MT_W][NT_W];
#pragma unroll
    for (int i = 0; i < MT_W; i++)
#pragma unroll
        for (int j = 0; j < NT_W; j++) acc[i][j] = (f4v){0.f, 0.f, 0.f, 0.f};

    for (int tap = 0; tap < 9; tap++) {
        const int dh = tap / 3 - 1, dw = tap % 3 - 1;
        const int dlo = dh * W + dw;
#pragma unroll
        for (int kk = 0; kk < KK; kk++) {
            s8v a[MT_W];
#pragma unroll
            for (int i = 0; i < MT_W; i++) {
                int nh = hh[i] + dh, nw = ww[i] + dw;
                bool ok = (nh >= 0) & (nh < H) & (nw < W) & (nw >= 0);
                // always in-bounds: lbase+i*16+dlo in [0, REG)
                s8v t = *(const s8v*)(smem + (lbase + i * 16 + dlo) * SE + kk * 32 + q * 8);
                a[i] = ok ? t : (s8v){0, 0, 0, 0, 0, 0, 0, 0};
            }
#pragma unroll
            for (int j = 0; j < NT_W; j++) {
                int co = (wn * NT_W + j) * 16 + lm;
                s8v b = *(const s8v*)(wb + ((long)(tap * COUT + co)) * CINP + kk * 32 + q * 8);
#pragma unroll
                for (int i = 0; i < MT_W; i++)
                    acc[i][j] = __builtin_amdgcn_mfma_f32_16x16x32_bf16(a[i], b, acc[i][j], 0, 0, 0);
            }
        }
    }

    float ls[NT_W], lq[NT_W];
#pragma unroll
    for (int j = 0; j < NT_W; j++) { ls[j] = 0.f; lq[j] = 0.f; }
    float lc = 0.f;
#pragma unroll
    for (int i = 0; i < MT_W; i++) {
#pragma unroll
        for (int r = 0; r < 4; r++) {
            long so = base + (mt0 + i) * 16 + q * 4 + r;
            float mk = mask[so];
            if (CNT) { if (wv == 0 && lm == 0) lc += (mk > 0.f) ? 1.f : 0.f; }
#pragma unroll
            for (int j = 0; j < NT_W; j++) {
                int co = (wn * NT_W + j) * 16 + lm;
                bf16 ob = f2b(mk > 0.f ? acc[i][j][r] : 0.f);
                out[so * COUT + co] = ob;
                if (STATS) { float vb = b2f(ob); ls[j] += vb; lq[j] += vb * vb; }
            }
        }
    }
    if (STATS) {
#pragma unroll
        for (int j = 0; j < NT_W; j++) {
            // fold the 4 q-groups (same lm) via shuffle; q==0 lanes atomic, conflict-free
            ls[j] += __shfl_xor(ls[j], 16);
            ls[j] += __shfl_xor(ls[j], 32);
            lq[j] += __shfl_xor(lq[j], 16);
            lq[j] += __shfl_xor(lq[j], 32);
            if (q == 0) {
                int co = (wn * NT_W + j) * 16 + lm;
                atomicAdd(&s_s[co], ls[j]);
                atomicAdd(&s_q[co], lq[j]);
            }
        }
        if (CNT) {
            lc += __shfl_xor(lc, 16);
            lc += __shfl_xor(lc, 32);
            if (wv == 0 && L == 0) atomicAdd(&s_c, lc);
        }
        __syncthreads();
        int bk = blockIdx.x & 63;
        if (tid < COUT) {
            atomicAdd(bktOut + (long)bk * 2 * COUT + tid, s_s[tid]);
            atomicAdd(bktOut + (long)bk * 2 * COUT + COUT + tid, s_q[tid]);
        }
        if (CNT && tid == 0) atomicAdd(cntOut, s_c);
    }
}

// ---------------- maxpool + in-block BN fold + affine/relu (C=32, b-major output) ----------------
template<int C>
__global__ void maxpool_bn(const bf16* __restrict__ in, const float* __restrict__ min_,
                           const float* __restrict__ bkt, const float* __restrict__ cnt,
                           const float* __restrict__ g, const float* __restrict__ b_,
                           bf16* __restrict__ out, float* __restrict__ mout,
                           int B, int H, int W, int OH, int OW) {
    __shared__ float ssc[C], ssh[C];
    int tid = threadIdx.x;
    if (tid < C) {
        float s = 0.f, q2 = 0.f;
        for (int k = 0; k < 64; k++) {
            s  += bkt[(long)k * 2 * C + tid];
            q2 += bkt[(long)k * 2 * C + C + tid];
        }
        float n = fmaxf(cnt[0], 1.f);
        float mean = s / n;
        float var  = q2 / n - mean * mean;
        float scv = (1.f / sqrtf(var + 1e-4f)) * g[tid];
        ssc[tid] = scv;
        ssh[tid] = b_[tid] - mean * scv;
    }
    __syncthreads();                                   // grid exact (5280*256) - all reach
    long i8 = (long)blockIdx.x * 256 + tid;
    long total8 = (long)B * OH * OW * C / 8;
    if (i8 >= total8) return;
    long e0 = i8 * 8;
    int c0 = (int)(e0 % C);
    long osite = e0 / C;
    int ow = (int)(osite % OW); long t2 = osite / OW; int oh = (int)(t2 % OH); long b = t2 / OH;
    float sc[8], sh[8];
#pragma unroll
    for (int i = 0; i < 8; i++) { sc[i] = ssc[c0 + i]; sh[i] = ssh[c0 + i]; }
    float mm = 0.f, p[8];
#pragma unroll
    for (int i = 0; i < 8; i++) p[i] = -1e30f;
    for (int kh = 0; kh < 3; kh++)
    for (int kw = 0; kw < 3; kw++) {
        int h = oh * 2 + kh, w = ow * 2 + kw;
        long is = ((long)b * H + h) * W + w;
        float mv = min_[is];
        if (mv > 0.f) {
            mm = 1.f;
            float f[8];
            ld8(in + is * C + c0, f);
#pragma unroll
            for (int i = 0; i < 8; i++) p[i] = fmaxf(p[i], f[i] * sc[i] + sh[i]);
        }
    }
    float o[8];
#pragma unroll
    for (int i = 0; i < 8; i++) o[i] = (mm > 0.f) ? fmaxf(p[i], 0.f) : 0.f;
    st8(out + e0, o);
    if (c0 == 0) mout[osite] = mm;
}

// ---------------- maxpool2 + in-block BN4 fold: c4 -> p2T8[k8][hw][b][8], m2h ----------------
__global__ void maxpool_p2t(const bf16* __restrict__ c4, const float* __restrict__ m1,
                            const float* __restrict__ bkt, const float* __restrict__ cnt,
                            const float* __restrict__ g, const float* __restrict__ b_,
                            bf16* __restrict__ p2T8, float* __restrict__ m2h) {
    __shared__ float ssc[128], ssh[128];
    int tid = threadIdx.x;
    if (tid < 128) {
        float s = 0.f, q2 = 0.f;
        for (int k = 0; k < 64; k++) {
            s  += bkt[(long)k * 256 + tid];
            q2 += bkt[(long)k * 256 + 128 + tid];
        }
        float n = fmaxf(cnt[0], 1.f);
        float mean = s / n;
        float var  = q2 / n - mean * mean;
        float scv = (1.f / sqrtf(var + 1e-4f)) * g[tid];
        ssc[tid] = scv;
        ssh[tid] = b_[tid] - mean * scv;
    }
    __syncthreads();                                   // grid exact (4480*256) - all reach
    int t = blockIdx.x * 256 + tid;                    // 16*35*2048 = 1,146,880
    if (t >= 1146880) return;
    int b  = t & 2047;
    int q2i = t >> 11;
    int hw = q2i % 35;
    int k8 = q2i / 35;
    int oh = hw / QW, ow = hw % QW;
    int c0 = k8 * 8;
    float sc[8], sh[8];
#pragma unroll
    for (int i = 0; i < 8; i++) { sc[i] = ssc[c0 + i]; sh[i] = ssh[c0 + i]; }
    float mm = 0.f, p[8];
#pragma unroll
    for (int i = 0; i < 8; i++) p[i] = -1e30f;
    for (int kh = 0; kh < 3; kh++)
    for (int kw = 0; kw < 3; kw++) {
        int h = oh * 2 + kh, w = ow * 2 + kw;
        long is = ((long)b * PH + h) * PW + w;
        float mv = m1[is];
        if (mv > 0.f) {
            mm = 1.f;
            float f[8];
            ld8(c4 + is * 128 + c0, f);
#pragma unroll
            for (int i = 0; i < 8; i++) p[i] = fmaxf(p[i], f[i] * sc[i] + sh[i]);
        }
    }
    float o[8];
#pragma unroll
    for (int i = 0; i < 8; i++) o[i] = (mm > 0.f) ? fmaxf(p[i], 0.f) : 0.f;
    st8(p2T8 + (long)t * 8, o);                      // t == (k8*35+hw)*2048+b exactly
    if (k8 == 0) m2h[hw * 2048 + b] = mm;
}

// ---------------- LSTM weight: Wl[tap][cin][1024] -> wbl3[tap][kk][n'=g*256+c][32] ----------------
// Must run AFTER maxpool_p2t (wbl3 overwrites dead-c4 space in bufA) -> cannot merge into cvt_all.
__global__ void cvt_wl3_k(const float* __restrict__ Wl, bf16* __restrict__ wbl3) {
    int idx = blockIdx.x * 256 + threadIdx.x;
    if (idx >= 884736) return;
    int kidx = idx & 31;
    int n    = (idx >> 5) % 768;
    int kk   = (idx >> 5) / 768 % 4;
    int tap  = idx / (32 * 768 * 4);
    int g = n >> 8, c = n & 255;
    int col = (g == 0) ? c : (g == 1 ? 512 + c : 768 + c);
    int cin = kk * 32 + kidx;
    wbl3[idx] = f2b(Wl[((long)(tap * 128 + cin)) * 1024 + col]);
}

// ---------------- ConvLSTM gates (v10 structure, measured best ~136-140 us) ----------------
__global__ void __launch_bounds__(256, 3)
gates_mfma(const bf16* __restrict__ p2T8, const bf16* __restrict__ wbl3,
           const float* __restrict__ bl, const float* __restrict__ m2h,
           bf16* __restrict__ goutT8) {
    __shared__ bf16 abuf[16 * 64 * 8];               // [kq][b][8] for current tap
    __shared__ bf16 sm[64][136];
    const int bi = blockIdx.x;
    const int half = bi & 1;
    const int g2 = bi >> 1;                          // 0..1119
    const int hw = g2 >> 5;                          // /32
    const int b0 = (g2 & 31) * 64;
    const int h = hw / QW, w = hw % QW;
    const int tid = threadIdx.x;
    const int wv = tid >> 6;
    const int L  = tid & 63;
    const int q  = L >> 4;
    const int lm = L & 15;

    f4v acc[4][2][3];
#pragma unroll
    for (int i = 0; i < 4; i++)
#pragma unroll
        for (int j = 0; j < 2; j++)
#pragma unroll
            for (int g = 0; g < 3; g++) acc[i][j][g] = (f4v){0.f, 0.f, 0.f, 0.f};

    for (int tap = 0; tap < 9; tap++) {
        const int dh = tap / 3 - 1, dw = tap % 3 - 1;
        const int nh = h + dh, nw = w + dw;
        if (nh < 0 || nh >= QH || nw < 0 || nw >= QW) continue;   // block-uniform skip
        const int hwn = hw + dh * QW + dw;

        __syncthreads();                              // prior tap's abuf reads done
        // stage A: 1024 x 16B chunks, chunk c = kq*64 + bb (coalesced 1KB/wave rounds)
        for (int c = tid; c < 1024; c += 256) {
            int kq = c >> 6;
            int bb = c & 63;
            uint4 v = *(const uint4*)(p2T8 + (((long)(kq * 35 + hwn)) * 2048 + b0 + bb) * 8);
            *(uint4*)(abuf + (long)c * 8) = v;
        }
        __syncthreads();

#pragma unroll
        for (int kk = 0; kk < 4; kk++) {
            s8v a[4];
#pragma unroll
            for (int i = 0; i < 4; i++)
                a[i] = *(const s8v*)(abuf + (((kk * 4 + q) * 64) + i * 16 + lm) * 8);
            const bf16* slab = wbl3 + ((long)(tap * 4 + kk)) * 768 * 32 + (long)q * 8;
#pragma unroll
            for (int j = 0; j < 2; j++) {
                int cc = half * 8 + wv * 2 + j;       // 0..15
#pragma unroll
                for (int g = 0; g < 3; g++) {
                    int n = g * 256 + cc * 16 + lm;
                    s8v b = *(const s8v*)(slab + (long)n * 32);
#pragma unroll
                    for (int i = 0; i < 4; i++)
                        acc[i][j][g] = __builtin_amdgcn_mfma_f32_16x16x32_bf16(a[i], b, acc[i][j][g], 0, 0, 0);
                }
            }
        }
    }
    // LSTM epilogue -> LDS
#pragma unroll
    for (int j = 0; j < 2; j++) {
        int cc = half * 8 + wv * 2 + j;
        int c = cc * 16 + lm;                        // global channel 0..255
        int cl = (wv * 2 + j) * 16 + lm;             // local 0..127
        float bi_ = bl[c], bo_ = bl[512 + c], bg_ = bl[768 + c];
#pragma unroll
        for (int i = 0; i < 4; i++) {
#pragma unroll
            for (int r = 0; r < 4; r++) {
                int b_in = i * 16 + q * 4 + r;
                float m = m2h[hw * 2048 + b0 + b_in];
                float val = 0.f;
                if (m > 0.f) {
                    float iv = acc[i][j][0][r] + bi_;
                    float ov = acc[i][j][1][r] + bo_;
                    float gv = acc[i][j][2][r] + bg_;
                    float ct = sigmoidf_(iv) * tanhf_(gv);
                    val = sigmoidf_(ov) * tanhf_(ct);
                }
                sm[b_in][cl] = f2b(val);
            }
        }
    }
    __syncthreads();
    // coalesced copy LDS -> goutT8: 1024 x 16B entries; entry e: c8l = e>>6, b_in = e&63
#pragma unroll
    for (int k = 0; k < 4; k++) {
        int e = k * 256 + tid;
        int c8l = e >> 6, b_in = e & 63;
        union { uint4 u; bf16 h8[8]; } v;
#pragma unroll
        for (int i = 0; i < 8; i++) v.h8[i] = sm[b_in][c8l * 8 + i];
        long dst = ((long)(hw * 32 + half * 16 + c8l)) * 2048 + b0 + b_in;
        *(uint4*)(goutT8 + dst * 8) = v.u;
    }
}

// ---------------- FC1 via MFMA, T8 layouts (fully coalesced fragment loads) ----------------
__global__ void fc1_mfma(const bf16* __restrict__ AT8, const bf16* __restrict__ WT8,
                         const float* __restrict__ lb1, bf16* __restrict__ y1) {
    const int tid = threadIdx.x;
    const int wv = tid >> 6;
    const int L  = tid & 63;
    const int q  = L >> 4, lm = L & 15;
    const int wm = wv >> 1, wn = wv & 1;
    const int bm = blockIdx.x & 31;
    const int bn = blockIdx.x >> 5;
    const int m0 = bm * 64 + wm * 32;
    const int n0 = bn * 64 + wn * 32;

    f4v acc[2][2];
#pragma unroll
    for (int i = 0; i < 2; i++)
#pragma unroll
        for (int j = 0; j < 2; j++) acc[i][j] = (f4v){0.f, 0.f, 0.f, 0.f};

#pragma unroll 2
    for (int k8 = 0; k8 < 1120; k8 += 4) {
        long ar = ((long)(k8 + q)) * 2048;
        long br = ((long)(k8 + q)) * 1024;
        s8v a0 = *(const s8v*)(AT8 + (ar + m0 + lm) * 8);
        s8v a1 = *(const s8v*)(AT8 + (ar + m0 + 16 + lm) * 8);
        s8v b0 = *(const s8v*)(WT8 + (br + n0 + lm) * 8);
        s8v b1 = *(const s8v*)(WT8 + (br + n0 + 16 + lm) * 8);
        acc[0][0] = __builtin_amdgcn_mfma_f32_16x16x32_bf16(a0, b0, acc[0][0], 0, 0, 0);
        acc[0][1] = __builtin_amdgcn_mfma_f32_16x16x32_bf16(a0, b1, acc[0][1], 0, 0, 0);
        acc[1][0] = __builtin_amdgcn_mfma_f32_16x16x32_bf16(a1, b0, acc[1][0], 0, 0, 0);
        acc[1][1] = __builtin_amdgcn_mfma_f32_16x16x32_bf16(a1, b1, acc[1][1], 0, 0, 0);
    }
#pragma unroll
    for (int i = 0; i < 2; i++) {
#pragma unroll
        for (int j = 0; j < 2; j++) {
            int nn = n0 + j * 16 + lm;
            float bias = lb1[nn];
#pragma unroll
            for (int r = 0; r < 4; r++) {
                int mm = m0 + i * 16 + q * 4 + r;
                y1[(long)mm * 1024 + nn] = f2b(fmaxf(acc[i][j][r] + bias, 0.f));
            }
        }
    }
}

// ---------------- FC2 via MFMA: y1[2048,1024] x (whi+wlo)[1024,448] + lb2 -> out[2048,420] ----------------
__global__ void fc2_mfma(const bf16* __restrict__ y1, const bf16* __restrict__ whi,
                         const bf16* __restrict__ wlo, const float* __restrict__ lb2,
                         float* __restrict__ out) {
    const int tid = threadIdx.x;
    const int wv = tid >> 6;
    const int L  = tid & 63;
    const int q  = L >> 4, lm = L & 15;
    const int wm = wv >> 1, wn = wv & 1;
    const int bm = blockIdx.x % 32;
    const int bn = blockIdx.x / 32;
    const int m0 = bm * 64 + wm * 32;
    const int n0 = bn * 64 + wn * 32;

    f4v acc[2][2];
#pragma unroll
    for (int i = 0; i < 2; i++)
#pragma unroll
        for (int j = 0; j < 2; j++) acc[i][j] = (f4v){0.f, 0.f, 0.f, 0.f};

#pragma unroll 2
    for (int k8 = 0; k8 < 128; k8 += 4) {
        const bf16* arow = y1 + (long)(k8 + q) * 8;
        long br = ((long)(k8 + q)) * 448;
        s8v a0 = *(const s8v*)(arow + (long)(m0 + lm) * 1024);
        s8v a1 = *(const s8v*)(arow + (long)(m0 + 16 + lm) * 1024);
        s8v h0 = *(const s8v*)(whi + (br + n0 + lm) * 8);
        s8v h1 = *(const s8v*)(whi + (br + n0 + 16 + lm) * 8);
        s8v l0 = *(const s8v*)(wlo + (br + n0 + lm) * 8);
        s8v l1 = *(const s8v*)(wlo + (br + n0 + 16 + lm) * 8);
        acc[0][0] = __builtin_amdgcn_mfma_f32_16x16x32_bf16(a0, h0, acc[0][0], 0, 0, 0);
        acc[0][1] = __builtin_amdgcn_mfma_f32_16x16x32_bf16(a0, h1, acc[0][1], 0, 0, 0);
        acc[1][0] = __builtin_amdgcn_mfma_f32_16x16x32_bf16(a1, h0, acc[1][0], 0, 0, 0);
        acc[1][1] = __builtin_amdgcn_mfma_f32_16x16x32_bf16(a1, h1, acc[1][1], 0, 0, 0);
        acc[0][0] = __builtin_amdgcn_mfma_f32_16x16x32_bf16(a0, l0, acc[0][0], 0, 0, 0);
        acc[0][1] = __builtin_amdgcn_mfma_f32_16x16x32_bf16(a0, l1, acc[0][1], 0, 0, 0);
        acc[1][0] = __builtin_amdgcn_mfma_f32_16x16x32_bf16(a1, l0, acc[1][0], 0, 0, 0);
        acc[1][1] = __builtin_amdgcn_mfma_f32_16x16x32_bf16(a1, l1, acc[1][1], 0, 0, 0);
    }
#pragma unroll
    for (int j = 0; j < 2; j++) {
        int nn = n0 + j * 16 + lm;
        if (nn >= 420) continue;
        float bias = lb2[nn];
#pragma unroll
        for (int i = 0; i < 2; i++) {
#pragma unroll
            for (int r = 0; r < 4; r++) {
                int mm = m0 + i * 16 + q * 4 + r;
                out[(long)mm * 420 + nn] = acc[i][j][r] + bias;
            }
        }
    }
}

// ---------------- launch ----------------
extern "C" void kernel_launch(void* const* d_in, const int* in_sizes, int n_in,
                              void* d_out, int out_size, void* d_ws, size_t ws_size,
                              hipStream_t stream) {
    const float* x    = (const float*)d_in[0];
    const int*   mask = (const int*)d_in[1];
    const float* W1 = (const float*)d_in[2];
    const float* g1 = (const float*)d_in[3];
    const float* b1 = (const float*)d_in[4];
    const float* W2 = (const float*)d_in[5];
    const float* g2 = (const float*)d_in[6];
    const float* b2 = (const float*)d_in[7];
    const float* W3 = (const float*)d_in[8];
    const float* g3 = (const float*)d_in[9];
    const float* b3 = (const float*)d_in[10];
    const float* W4 = (const float*)d_in[11];
    const float* g4 = (const float*)d_in[12];
    const float* b4 = (const float*)d_in[13];
    const float* Wl = (const float*)d_in[14];
    const float* bl = (const float*)d_in[15];
    const float* lw1 = (const float*)d_in[16];
    const float* lb1 = (const float*)d_in[17];
    const float* lw2 = (const float*)d_in[18];
    const float* lb2 = (const float*)d_in[19];
    float* out = (float*)d_out;

    float* ws = (float*)d_ws;
    float* m0 = ws + OFF_M0;
    float* m1 = ws + OFF_M1;
    float* m2h = ws + OFF_M2;
    bf16* bufA = (bf16*)(ws + OFF_BF);
    bf16* bufB = bufA + SZ_A;

    bf16* c1     = bufA;          // [NSITE1,16]
    bf16* xm     = bufB;          // [NSITE1,2]
    bf16* c2     = bufB;          // [NSITE1,32]
    bf16* p1     = bufA;          // [NSITE2,32]
    bf16* c3     = bufB;          // [NSITE2,64]
    bf16* c4     = bufA;          // [NSITE2,128]
    bf16* p2T8   = bufB;          // [16][35][2048][8]
    bf16* goutT8 = bufA;          // [1120][2048][8]
    bf16* y1     = bufB;          // [2048,1024]
    bf16* wb2    = bufA + WB2_A;
    bf16* wb3    = bufB + WB3_B;
    bf16* wb4    = bufB + WB4_B;
    bf16* wbl3   = bufA + WBL_A;
    bf16* wfc1   = bufB + WFC1_B;
    bf16* wfc2h  = bufB + WFC2_B;           // [128][448][8]
    bf16* wfc2l  = wfc2h + 458752;

    // f32 stat buckets in dead regions (see lifetime notes at the BKT_* constants)
    float* bkt16  = (float*)(bufA + BKT_A);            //  64*2*16  = 2048 f
    float* bkt32  = bkt16 + 2048;                      //  64*2*32  = 4096 f
    float* bkt64  = (float*)(bufB + BKT_B);            //  64*2*64  = 8192 f
    float* bkt128 = bkt64 + 8192;                      //  64*2*128 = 16384 f

    hipMemsetAsync(ws, 0, 4096, stream);               // BN counts
    hipMemsetAsync(bkt16, 0, (2048 + 4096) * 4, stream);

    // prep + W2 cvt merged (5704 + 36 blocks)
    prep_cvtw2_k<<<5740, 256, 0, stream>>>(x, mask, m0, xm, W2, wb2);

    // conv1 with fused BN1-stats (shuffle-reduced) + N1 count
    conv1_k<<<5704, 256, 0, stream>>>(xm, W1, m0, c1, bkt16, ws + OFF_N1);

    // conv2: in-block BN1 fold + staged apply + fused BN2-stats
    conv_mfma<16, 32, 32, 1, 2, 1, IH, IW, true, true, true, false>
        <<<(int)(NSITE1 / 64), 256, 0, stream>>>(c1, wb2, m0,
                                                 bkt16, ws + OFF_N1, g1, b1,
                                                 c2, bkt32, nullptr);

    // pool1: in-block BN2 fold + affine/relu
    maxpool_bn<32><<<(int)(NSITE2 * 32 / 8 / 256), 256, 0, stream>>>(
        c2, m0, bkt32, ws + OFF_N1, g2, b2, p1, m1, BB, IH, IW, PH, PW);

    // c2 (bufB) dead: zero bkt64+bkt128, then merged weight converts into bufB slack
    hipMemsetAsync(bkt64, 0, (8192 + 16384) * 4, stream);
    cvt_all_k<<<5064, 256, 0, stream>>>(W3, W4, lw1, lw2, wb3, wb4, wfc1, wfc2h, wfc2l);

    // conv3: input already BN'd by pool; fused BN3-stats + N2 count
    conv_mfma<32, 32, 64, 1, 4, 1, PH, PW, false, false, true, true>
        <<<(int)(NSITE2 / 64), 256, 0, stream>>>(p1, wb3, m1,
                                                 nullptr, nullptr, nullptr, nullptr,
                                                 c3, bkt64, ws + OFF_N2);

    // conv4: in-block BN3 fold + staged apply + fused BN4-stats
    conv_mfma<64, 64, 128, 2, 4, 2, PH, PW, false, true, true, false>
        <<<(int)(NSITE2 / 64), 256, 0, stream>>>(c3, wb4, m1,
                                                 bkt64, ws + OFF_N2, g3, b3,
                                                 c4, bkt128, nullptr);

    // pool2: in-block BN4 fold -> p2T8 + m2h
    maxpool_p2t<<<4480, 256, 0, stream>>>(c4, m1, bkt128, ws + OFF_N2, g4, b4, p2T8, m2h);

    // c4 (bufA) dead: convert wbl3 into bufA past goutT8's end
    cvt_wl3_k<<<(884736 + 255) / 256, 256, 0, stream>>>(Wl, wbl3);

    gates_mfma<<<2240, 256, 0, stream>>>(p2T8, wbl3, bl, m2h, goutT8);

    fc1_mfma<<<512, 256, 0, stream>>>(goutT8, wfc1, lb1, y1);

    fc2_mfma<<<224, 256, 0, stream>>>(y1, wfc2h, wfc2l, lb2, out);
}

// Round 16
// 888.868 us; speedup vs baseline: 1.0071x; 1.0071x over previous
//
#include <hip/hip_runtime.h>
#include <hip/hip_bf16.h>
#include <math.h>

using bf16 = __hip_bfloat16;

typedef short s8v __attribute__((ext_vector_type(8)));   // 8 bf16 bit-pattern (4 VGPRs)
typedef float f4v __attribute__((ext_vector_type(4)));   // MFMA accumulator

// ---------------- problem dims ----------------
static constexpr int  BB  = 2048;
static constexpr int  IH  = 23, IW = 31;   // stage 1 spatial
static constexpr int  PH  = 11, PW = 15;   // after pool1
static constexpr int  QH  = 5,  QW = 7;    // after pool2
static constexpr long NSITE1 = (long)BB * IH * IW;   // 1,460,224 = 5704*256
static constexpr long NSITE2 = (long)BB * PH * PW;   //   337,920
static constexpr long NSITE3 = (long)BB * QH * QW;   //    71,680

// ---------------- workspace layout ----------------
static constexpr long OFF_N1 = 640, OFF_N2 = 641;
static constexpr long OFF_M0 = 2048;
static constexpr long OFF_M1 = OFF_M0 + NSITE1;
static constexpr long OFF_M2 = OFF_M1 + NSITE2;      // m2h: hw-major mask [hw*2048+b]
static constexpr long OFF_BF = 1871872;              // float offset where bf16 area starts
static constexpr long SZ_A   = 43253760L;            // bf16 elems per region
static constexpr long WB2_A  = 25000000L;  // [9][32][32]
static constexpr long WB3_B  = 22000000L;  // [9][64][32]
static constexpr long WB4_B  = 22100000L;  // [9][128][64]
static constexpr long WBL_A  = 20000000L;  // [9][4][768][32] = 884,736
static constexpr long WFC1_B = 23000000L;  // wfc1T8 [1120][1024][8] = 9,175,040
static constexpr long WFC2_B = 33000000L;  // wfc2 hi/lo T8 [128][448][8] x2 = 917,504 (ends 33,917,504)
static constexpr long BKT_A  = 40000000L;  // bufA+40M bf16: f32 bkt16|bkt32 (6144 f)
static constexpr long BKT_B  = 34000000L;  // bufB+34M bf16: f32 bkt64|bkt128 (24576 f)
// Bucket lifetime safety (conv4 folds BN3 ITSELF, so bkt64 must survive conv4's writes):
//  bkt16/32 in bufA+40M: written by conv1/conv2 atomics, read by conv2/maxpool_bn folds;
//    bufA>=40M untouched in that window (c1 ends 23.4M; p1 ends 10.8M).
//  bkt64/128 in bufB+34M: written by conv3/conv4 atomics, read by conv4/maxpool_p2t folds;
//    conv4 writes c4 in bufA only; p2T8 ends 18.35M; wfc2 ends 33.92M. No overlap.

__device__ __forceinline__ float b2f(bf16 v) { return __bfloat162float(v); }
__device__ __forceinline__ bf16  f2b(float v) { return __float2bfloat16(v); }
__device__ __forceinline__ float sigmoidf_(float x) {
    return __builtin_amdgcn_rcpf(1.f + __expf(-x));
}
// fast tanh: clamp keeps exp finite; (1-t)/(1+t) with rcp. |err| ~1e-6, fine for bf16 out.
__device__ __forceinline__ float tanhf_(float x) {
    float xc = fminf(fmaxf(x, -15.f), 15.f);
    float t = __expf(-2.f * xc);
    return (1.f - t) * __builtin_amdgcn_rcpf(1.f + t);
}

__device__ __forceinline__ void ld8(const bf16* p, float* f) {
    union { uint4 u; unsigned short s[8]; } cv;
    cv.u = *(const uint4*)p;
#pragma unroll
    for (int i = 0; i < 8; i++) f[i] = __uint_as_float(((unsigned int)cv.s[i]) << 16);
}
__device__ __forceinline__ void st8(bf16* p, const float* f) {
    union { uint4 u; bf16 h[8]; } cv;
#pragma unroll
    for (int i = 0; i < 8; i++) cv.h[i] = f2b(f[i]);
    *(uint4*)p = cv.u;
}

// ---------------- inline weight-cvt body: W[tap][cin][cout] f32 -> wb[tap][cout][cinp] bf16 ----
__device__ __forceinline__ void cvt_w_body(const float* __restrict__ W, bf16* __restrict__ wb,
                                           int CIN, int CINP, int COUT, int total, int idx) {
    if (idx >= total) return;
    int ci  = idx % CINP;
    int t2  = idx / CINP;
    int co  = t2 % COUT;
    int tap = t2 / COUT;
    wb[idx] = (ci < CIN) ? f2b(W[((long)(tap * CIN + ci)) * COUT + co]) : f2b(0.f);
}

// ---------------- prep + W2 cvt merged (independent; saves a launch) ----------------
__global__ void prep_cvtw2_k(const float* __restrict__ x, const int* __restrict__ mask,
                             float* __restrict__ m0, bf16* __restrict__ xm,
                             const float* __restrict__ W2, bf16* __restrict__ wb2) {
    int bid = blockIdx.x, tid = threadIdx.x;
    if (bid < 5704) {                                 // prep: NSITE1 exact
        long idx = (long)bid * 256 + tid;
        float m = (mask[idx] != 0) ? 1.f : 0.f;
        m0[idx] = m;
        xm[idx * 2 + 0] = f2b(x[idx * 2 + 0] * m);
        xm[idx * 2 + 1] = f2b(x[idx * 2 + 1] * m);
    } else {                                          // cvt W2: 9216 elems, 36 blocks
        cvt_w_body(W2, wb2, 16, 32, 32, 9216, (bid - 5704) * 256 + tid);
    }
}

// ---------------- merged weight converts (W3 | W4 | fc1T8 | fc2T8) ----------------
__global__ void cvt_all_k(const float* __restrict__ W3, const float* __restrict__ W4,
                          const float* __restrict__ lw1, const float* __restrict__ lw2,
                          bf16* __restrict__ wb3, bf16* __restrict__ wb4,
                          bf16* __restrict__ wfc1, bf16* __restrict__ whi,
                          bf16* __restrict__ wlo) {
    int bid = blockIdx.x, tid = threadIdx.x;
    if (bid < 72) {                                   // W3: 18432
        cvt_w_body(W3, wb3, 32, 32, 64, 18432, bid * 256 + tid);
    } else if (bid < 360) {                           // W4: 73728
        cvt_w_body(W4, wb4, 64, 64, 128, 73728, (bid - 72) * 256 + tid);
    } else if (bid < 4840) {                          // fc1T8: 1,146,880 exact
        int t = (bid - 360) * 256 + tid;
        int j   = t & 1023;
        int k8g = t >> 10;
        int hw  = k8g >> 5;
        int c8  = k8g & 31;
        float f[8];
#pragma unroll
        for (int c7 = 0; c7 < 8; c7++)
            f[c7] = lw1[((long)((c8 * 8 + c7) * 35 + hw)) * 1024 + j];
        st8(wfc1 + (long)t * 8, f);
    } else {                                          // fc2T8: 57,344 exact (224 blocks)
        int t = (bid - 4840) * 256 + tid;
        int n  = t % 448;
        int k8 = t / 448;
        union { uint4 u; bf16 h8[8]; } h, l;
#pragma unroll
        for (int ki = 0; ki < 8; ki++) {
            float v = (n < 420) ? lw2[(long)(k8 * 8 + ki) * 420 + n] : 0.f;
            bf16 hb = f2b(v);
            h.h8[ki] = hb;
            l.h8[ki] = f2b(v - b2f(hb));
        }
        *(uint4*)(whi + (long)t * 8) = h.u;
        *(uint4*)(wlo + (long)t * 8) = l.u;
    }
}

// ---------------- conv1: 2->16, fused BN1-stats via wave shuffle reduction + N1 count ----------------
__global__ void conv1_k(const bf16* __restrict__ xm, const float* __restrict__ Wt,
                        const float* __restrict__ m0, bf16* __restrict__ out,
                        float* __restrict__ bkt, float* __restrict__ cnt) {
    __shared__ float s_s[16], s_q[16], s_c;
    const int H = IH, W = IW;
    int tid = threadIdx.x;
    int L = tid & 63;
    if (tid < 16) { s_s[tid] = 0.f; s_q[tid] = 0.f; }
    if (tid == 0) s_c = 0.f;
    __syncthreads();
    long site = (long)blockIdx.x * 256 + tid;        // grid exact: NSITE1 = 5704*256
    float acc[16];
#pragma unroll
    for (int i = 0; i < 16; i++) acc[i] = 0.f;
    float mk = 0.f;
    if (site < NSITE1) {
        mk = m0[site];
        if (mk > 0.f) {
            int w = (int)(site % W); int h = (int)((site / W) % H);
            for (int tap = 0; tap < 9; tap++) {
                int dh = tap / 3 - 1, dw = tap % 3 - 1;
                int nh = h + dh, nw = w + dw;
                if (nh < 0 || nh >= H || nw < 0 || nw >= W) continue;
                long ns = site + (long)dh * W + dw;
                float i0 = b2f(xm[ns * 2 + 0]), i1 = b2f(xm[ns * 2 + 1]);
                const float* wp = Wt + tap * 32;
#pragma unroll
                for (int co = 0; co < 16; co++) acc[co] += i0 * wp[co] + i1 * wp[16 + co];
            }
        }
        st8(out + site * 16, acc);
        st8(out + site * 16 + 8, acc + 8);
    }
    // stats on bf16-rounded stored values; wave butterfly then lane0 atomics
#pragma unroll
    for (int i = 0; i < 16; i++) {
        float vb = (site < NSITE1) ? b2f(f2b(acc[i])) : 0.f;
        float s = vb, q2 = vb * vb;
#pragma unroll
        for (int off = 32; off > 0; off >>= 1) {
            s  += __shfl_xor(s, off);
            q2 += __shfl_xor(q2, off);
        }
        if (L == 0) { atomicAdd(&s_s[i], s); atomicAdd(&s_q[i], q2); }
    }
    {
        float c = (mk > 0.f) ? 1.f : 0.f;
#pragma unroll
        for (int off = 32; off > 0; off >>= 1) c += __shfl_xor(c, off);
        if (L == 0) atomicAdd(&s_c, c);
    }
    __syncthreads();
    int bk = blockIdx.x & 63;
    if (tid < 16) {
        atomicAdd(bkt + (long)bk * 32 + tid, s_s[tid]);
        atomicAdd(bkt + (long)bk * 32 + 16 + tid, s_q[tid]);
    }
    if (tid == 0) atomicAdd(cnt, s_c);
}

// ---------------- MFMA direct conv 3x3 SAME, LDS-staged A (b-major sites) ----------------
// BN: fold 64-bucket input stats -> scale/shift IN-BLOCK, then fuse affine+ReLU+mask into
// staging. STATS: per-channel sum/sumsq of the bf16-rounded output into 64-way buckets,
// cross-q shuffle-folded (round-13/14 lesson: q-aliased LDS atomics = 5.67M conflicts).
template<int CIN, int CINP, int COUT, int KK, int MT_W, int NT_W, int H, int W,
         bool ZPAD, bool BN, bool STATS, bool CNT>
__global__ void conv_mfma(const bf16* __restrict__ in, const bf16* __restrict__ wb,
                          const float* __restrict__ mask,
                          const float* __restrict__ bktIn, const float* __restrict__ cntIn,
                          const float* __restrict__ gIn, const float* __restrict__ bIn,
                          bf16* __restrict__ out,
                          float* __restrict__ bktOut, float* __restrict__ cntOut) {
    constexpr int NT   = COUT / 16;
    constexpr int NWN  = NT / NT_W;
    constexpr int HALO = W + 1;
    constexpr int REG  = 64 + 2 * HALO;     // staged sites
    constexpr int SE   = CIN + 8;           // LDS site stride (elems), +16B pad
    constexpr int CHPS = CIN / 8;           // 16B chunks per site
    __shared__ bf16 smem[(REG + 1) * SE];
    __shared__ float s_s[COUT], s_q[COUT], s_c;
    __shared__ float s_sc[CIN], s_sh[CIN];

    const int tid = threadIdx.x;
    const int wv = tid >> 6;
    const int L  = tid & 63;
    const int q  = (L >> 4);
    const int lm = L & 15;
    const int wn = wv % NWN;
    const int wm = wv / NWN;
    const int mt0 = wm * MT_W;
    const long base = (long)blockIdx.x * 64;
    const long nsites = (long)gridDim.x * 64;

    if (BN) {
        if (tid < CIN) {
            float s = 0.f, q2 = 0.f;
            for (int k = 0; k < 64; k++) {
                s  += bktIn[(long)k * 2 * CIN + tid];
                q2 += bktIn[(long)k * 2 * CIN + CIN + tid];
            }
            float n = fmaxf(cntIn[0], 1.f);
            float mean = s / n;
            float var  = q2 / n - mean * mean;
            float scv = (1.f / sqrtf(var + 1e-4f)) * gIn[tid];
            s_sc[tid] = scv;
            s_sh[tid] = bIn[tid] - mean * scv;
        }
        __syncthreads();
    }

    // ---- stage A halo into LDS (reg-staged; padded stride forbids global_load_lds) ----
    for (int c = tid; c < REG * CHPS; c += 256) {
        int s = c / CHPS;
        int o = c % CHPS;
        long gs = base - HALO + s;
        uint4 v = {0u, 0u, 0u, 0u};
        if (gs >= 0 && gs < nsites) {
            v = *(const uint4*)(in + gs * CIN + o * 8);
            if (BN) {
                float mk = mask[gs];
                union { uint4 u; unsigned short us[8]; } cv; cv.u = v;
                union { uint4 u; bf16 h[8]; } ov;
#pragma unroll
                for (int i = 0; i < 8; i++) {
                    float f = __uint_as_float(((unsigned int)cv.us[i]) << 16);
                    int ch = o * 8 + i;
                    float r = fmaxf(f * s_sc[ch] + s_sh[ch], 0.f);
                    ov.h[i] = f2b(mk > 0.f ? r : 0.f);
                }
                v = ov.u;
            }
        }
        *(uint4*)(smem + s * SE + o * 8) = v;
    }
    if (ZPAD) {
        uint4 z = {0u, 0u, 0u, 0u};
        for (int s = tid; s < REG; s += 256)
            *(uint4*)(smem + s * SE + CIN) = z;              // per-site pad lane
        if (tid == 0)
            *(uint4*)(smem + REG * SE) = z;                  // tail (last site's q=3 over-read)
    }
    if (STATS) {
        if (tid < COUT) { s_s[tid] = 0.f; s_q[tid] = 0.f; }
        if (tid == 0) s_c = 0.f;
    }
    __syncthreads();

    int hh[MT_W], ww[MT_W];
#pragma unroll
    for (int i = 0; i < MT_W; i++) {
        long s = base + (mt0 + i) * 16 + lm;
        ww[i] = (int)(s % W);
        hh[i] = (int)((s / W) % H);
    }
    const int lbase = mt0 * 16 + lm + HALO;   // local site idx of this lane's tile row 0

    f4v acc[MT_W][NT_W];
#pragma unroll
    for (int i = 0; i < MT_W; i++)
#pragma unroll
        for (int j = 0; j < NT_W; j++) acc[i][j] = (f4v){0.f, 0.f, 0.f, 0.f};

    for (int tap = 0; tap < 9; tap++) {
        const int dh = tap / 3 - 1, dw = tap % 3 - 1;
        const int dlo = dh * W + dw;
#pragma unroll
        for (int kk = 0; kk < KK; kk++) {
            s8v a[MT_W];
#pragma unroll
            for (int i = 0; i < MT_W; i++) {
                int nh = hh[i] + dh, nw = ww[i] + dw;
                bool ok = (nh >= 0) & (nh < H) & (nw < W) & (nw >= 0);
                // always in-bounds: lbase+i*16+dlo in [0, REG)
                s8v t = *(const s8v*)(smem + (lbase + i * 16 + dlo) * SE + kk * 32 + q * 8);
                a[i] = ok ? t : (s8v){0, 0, 0, 0, 0, 0, 0, 0};
            }
#pragma unroll
            for (int j = 0; j < NT_W; j++) {
                int co = (wn * NT_W + j) * 16 + lm;
                s8v b = *(const s8v*)(wb + ((long)(tap * COUT + co)) * CINP + kk * 32 + q * 8);
#pragma unroll
                for (int i = 0; i < MT_W; i++)
                    acc[i][j] = __builtin_amdgcn_mfma_f32_16x16x32_bf16(a[i], b, acc[i][j], 0, 0, 0);
            }
        }
    }

    float ls[NT_W], lq[NT_W];
#pragma unroll
    for (int j = 0; j < NT_W; j++) { ls[j] = 0.f; lq[j] = 0.f; }
    float lc = 0.f;
#pragma unroll
    for (int i = 0; i < MT_W; i++) {
#pragma unroll
        for (int r = 0; r < 4; r++) {
            long so = base + (mt0 + i) * 16 + q * 4 + r;
            float mk = mask[so];
            if (CNT) { if (wv == 0 && lm == 0) lc += (mk > 0.f) ? 1.f : 0.f; }
#pragma unroll
            for (int j = 0; j < NT_W; j++) {
                int co = (wn * NT_W + j) * 16 + lm;
                bf16 ob = f2b(mk > 0.f ? acc[i][j][r] : 0.f);
                out[so * COUT + co] = ob;
                if (STATS) { float vb = b2f(ob); ls[j] += vb; lq[j] += vb * vb; }
            }
        }
    }
    if (STATS) {
#pragma unroll
        for (int j = 0; j < NT_W; j++) {
            // fold the 4 q-groups (same lm) via shuffle; q==0 lanes atomic, conflict-free
            ls[j] += __shfl_xor(ls[j], 16);
            ls[j] += __shfl_xor(ls[j], 32);
            lq[j] += __shfl_xor(lq[j], 16);
            lq[j] += __shfl_xor(lq[j], 32);
            if (q == 0) {
                int co = (wn * NT_W + j) * 16 + lm;
                atomicAdd(&s_s[co], ls[j]);
                atomicAdd(&s_q[co], lq[j]);
            }
        }
        if (CNT) {
            lc += __shfl_xor(lc, 16);
            lc += __shfl_xor(lc, 32);
            if (wv == 0 && L == 0) atomicAdd(&s_c, lc);
        }
        __syncthreads();
        int bk = blockIdx.x & 63;
        if (tid < COUT) {
            atomicAdd(bktOut + (long)bk * 2 * COUT + tid, s_s[tid]);
            atomicAdd(bktOut + (long)bk * 2 * COUT + COUT + tid, s_q[tid]);
        }
        if (CNT && tid == 0) atomicAdd(cntOut, s_c);
    }
}

// ---------------- maxpool + in-block BN fold + affine/relu (C=32, b-major output) ----------------
template<int C>
__global__ void maxpool_bn(const bf16* __restrict__ in, const float* __restrict__ min_,
                           const float* __restrict__ bkt, const float* __restrict__ cnt,
                           const float* __restrict__ g, const float* __restrict__ b_,
                           bf16* __restrict__ out, float* __restrict__ mout,
                           int B, int H, int W, int OH, int OW) {
    __shared__ float ssc[C], ssh[C];
    int tid = threadIdx.x;
    if (tid < C) {
        float s = 0.f, q2 = 0.f;
        for (int k = 0; k < 64; k++) {
            s  += bkt[(long)k * 2 * C + tid];
            q2 += bkt[(long)k * 2 * C + C + tid];
        }
        float n = fmaxf(cnt[0], 1.f);
        float mean = s / n;
        float var  = q2 / n - mean * mean;
        float scv = (1.f / sqrtf(var + 1e-4f)) * g[tid];
        ssc[tid] = scv;
        ssh[tid] = b_[tid] - mean * scv;
    }
    __syncthreads();                                   // grid exact (5280*256) - all reach
    long i8 = (long)blockIdx.x * 256 + tid;
    long total8 = (long)B * OH * OW * C / 8;
    if (i8 >= total8) return;
    long e0 = i8 * 8;
    int c0 = (int)(e0 % C);
    long osite = e0 / C;
    int ow = (int)(osite % OW); long t2 = osite / OW; int oh = (int)(t2 % OH); long b = t2 / OH;
    float sc[8], sh[8];
#pragma unroll
    for (int i = 0; i < 8; i++) { sc[i] = ssc[c0 + i]; sh[i] = ssh[c0 + i]; }
    float mm = 0.f, p[8];
#pragma unroll
    for (int i = 0; i < 8; i++) p[i] = -1e30f;
    for (int kh = 0; kh < 3; kh++)
    for (int kw = 0; kw < 3; kw++) {
        int h = oh * 2 + kh, w = ow * 2 + kw;
        long is = ((long)b * H + h) * W + w;
        float mv = min_[is];
        if (mv > 0.f) {
            mm = 1.f;
            float f[8];
            ld8(in + is * C + c0, f);
#pragma unroll
            for (int i = 0; i < 8; i++) p[i] = fmaxf(p[i], f[i] * sc[i] + sh[i]);
        }
    }
    float o[8];
#pragma unroll
    for (int i = 0; i < 8; i++) o[i] = (mm > 0.f) ? fmaxf(p[i], 0.f) : 0.f;
    st8(out + e0, o);
    if (c0 == 0) mout[osite] = mm;
}

// ---------------- maxpool2 + in-block BN4 fold: c4 -> p2T8[k8][hw][b][8], m2h ----------------
__global__ void maxpool_p2t(const bf16* __restrict__ c4, const float* __restrict__ m1,
                            const float* __restrict__ bkt, const float* __restrict__ cnt,
                            const float* __restrict__ g, const float* __restrict__ b_,
                            bf16* __restrict__ p2T8, float* __restrict__ m2h) {
    __shared__ float ssc[128], ssh[128];
    int tid = threadIdx.x;
    if (tid < 128) {
        float s = 0.f, q2 = 0.f;
        for (int k = 0; k < 64; k++) {
            s  += bkt[(long)k * 256 + tid];
            q2 += bkt[(long)k * 256 + 128 + tid];
        }
        float n = fmaxf(cnt[0], 1.f);
        float mean = s / n;
        float var  = q2 / n - mean * mean;
        float scv = (1.f / sqrtf(var + 1e-4f)) * g[tid];
        ssc[tid] = scv;
        ssh[tid] = b_[tid] - mean * scv;
    }
    __syncthreads();                                   // grid exact (4480*256) - all reach
    int t = blockIdx.x * 256 + tid;                    // 16*35*2048 = 1,146,880
    if (t >= 1146880) return;
    int b  = t & 2047;
    int q2i = t >> 11;
    int hw = q2i % 35;
    int k8 = q2i / 35;
    int oh = hw / QW, ow = hw % QW;
    int c0 = k8 * 8;
    float sc[8], sh[8];
#pragma unroll
    for (int i = 0; i < 8; i++) { sc[i] = ssc[c0 + i]; sh[i] = ssh[c0 + i]; }
    float mm = 0.f, p[8];
#pragma unroll
    for (int i = 0; i < 8; i++) p[i] = -1e30f;
    for (int kh = 0; kh < 3; kh++)
    for (int kw = 0; kw < 3; kw++) {
        int h = oh * 2 + kh, w = ow * 2 + kw;
        long is = ((long)b * PH + h) * PW + w;
        float mv = m1[is];
        if (mv > 0.f) {
            mm = 1.f;
            float f[8];
            ld8(c4 + is * 128 + c0, f);
#pragma unroll
            for (int i = 0; i < 8; i++) p[i] = fmaxf(p[i], f[i] * sc[i] + sh[i]);
        }
    }
    float o[8];
#pragma unroll
    for (int i = 0; i < 8; i++) o[i] = (mm > 0.f) ? fmaxf(p[i], 0.f) : 0.f;
    st8(p2T8 + (long)t * 8, o);                      // t == (k8*35+hw)*2048+b exactly
    if (k8 == 0) m2h[hw * 2048 + b] = mm;
}

// ---------------- LSTM weight: Wl[tap][cin][1024] -> wbl3[tap][kk][n'=g*256+c][32] ----------------
// Must run AFTER maxpool_p2t (wbl3 overwrites dead-c4 space in bufA) -> cannot merge into cvt_all.
__global__ void cvt_wl3_k(const float* __restrict__ Wl, bf16* __restrict__ wbl3) {
    int idx = blockIdx.x * 256 + threadIdx.x;
    if (idx >= 884736) return;
    int kidx = idx & 31;
    int n    = (idx >> 5) % 768;
    int kk   = (idx >> 5) / 768 % 4;
    int tap  = idx / (32 * 768 * 4);
    int g = n >> 8, c = n & 255;
    int col = (g == 0) ? c : (g == 1 ? 512 + c : 768 + c);
    int cin = kk * 32 + kidx;
    wbl3[idx] = f2b(Wl[((long)(tap * 128 + cin)) * 1024 + col]);
}

// ---------------- ConvLSTM gates v16: v10 structure + 2-tap-per-barrier staging ----------------
// v10 floor was 136 us vs 41 us MFMA floor; cost = per-tap {barrier, 16KB L2 stage, barrier}
// events at ~2.4 waves/SIMD. v16 stages TWO valid taps per barrier pair (abuf[2], 8 loads
// in flight per thread) -> stall events ~halve (7.06 -> ~3.9 avg), bytes unchanged.
// Avoids v9's spill (no regs live across MFMA) and v11's occupancy loss (LDS 32+17.4 =
// 49.4 KB -> still 3 blocks/CU = 148 KB; block shape unchanged). All control block-uniform.
__global__ void __launch_bounds__(256, 3)
gates_mfma(const bf16* __restrict__ p2T8, const bf16* __restrict__ wbl3,
           const float* __restrict__ bl, const float* __restrict__ m2h,
           bf16* __restrict__ goutT8) {
    __shared__ bf16 abuf[2][16 * 64 * 8];            // two tap slabs [kq][b][8]
    __shared__ bf16 sm[64][136];
    const int bi = blockIdx.x;
    const int half = bi & 1;
    const int g2 = bi >> 1;                          // 0..1119
    const int hw = g2 >> 5;                          // /32
    const int b0 = (g2 & 31) * 64;
    const int h = hw / QW, w = hw % QW;
    const int tid = threadIdx.x;
    const int wv = tid >> 6;
    const int L  = tid & 63;
    const int q  = L >> 4;
    const int lm = L & 15;

    f4v acc[4][2][3];
#pragma unroll
    for (int i = 0; i < 4; i++)
#pragma unroll
        for (int j = 0; j < 2; j++)
#pragma unroll
            for (int g = 0; g < 3; g++) acc[i][j][g] = (f4v){0.f, 0.f, 0.f, 0.f};

    auto tap_ok = [&](int tap) {
        int nh = h + tap / 3 - 1, nw = w + tap % 3 - 1;
        return (nh >= 0) && (nh < QH) && (nw >= 0) && (nw < QW);
    };

    int t = 0;
    while (t < 9) {                                   // block-uniform control throughout
        while (t < 9 && !tap_ok(t)) t++;
        if (t >= 9) break;
        int t0 = t++;
        while (t < 9 && !tap_ok(t)) t++;
        int t1 = (t < 9) ? t++ : -1;

        __syncthreads();                              // prior pair's abuf reads done
        {
            int hwn = hw + (t0 / 3 - 1) * QW + (t0 % 3 - 1);
#pragma unroll
            for (int r = 0; r < 4; r++) {
                int c = tid + r * 256;
                int kq = c >> 6, bb = c & 63;
                uint4 v = *(const uint4*)(p2T8 + (((long)(kq * 35 + hwn)) * 2048 + b0 + bb) * 8);
                *(uint4*)(&abuf[0][0] + (long)c * 8) = v;
            }
        }
        if (t1 >= 0) {
            int hwn = hw + (t1 / 3 - 1) * QW + (t1 % 3 - 1);
#pragma unroll
            for (int r = 0; r < 4; r++) {
                int c = tid + r * 256;
                int kq = c >> 6, bb = c & 63;
                uint4 v = *(const uint4*)(p2T8 + (((long)(kq * 35 + hwn)) * 2048 + b0 + bb) * 8);
                *(uint4*)(&abuf[1][0] + (long)c * 8) = v;
            }
        }
        __syncthreads();                              // both slabs ready

        for (int s = 0; s < 2; s++) {                 // uniform (t1 uniform per block)
            int tap = (s == 0) ? t0 : t1;
            if (tap < 0) break;
            const bf16* ab = &abuf[s][0];
#pragma unroll
            for (int kk = 0; kk < 4; kk++) {
                s8v a[4];
#pragma unroll
                for (int i = 0; i < 4; i++)
                    a[i] = *(const s8v*)(ab + (((kk * 4 + q) * 64) + i * 16 + lm) * 8);
                const bf16* slab = wbl3 + ((long)(tap * 4 + kk)) * 768 * 32 + (long)q * 8;
#pragma unroll
                for (int j = 0; j < 2; j++) {
                    int cc = half * 8 + wv * 2 + j;   // 0..15
#pragma unroll
                    for (int g = 0; g < 3; g++) {
                        int n = g * 256 + cc * 16 + lm;
                        s8v b = *(const s8v*)(slab + (long)n * 32);
#pragma unroll
                        for (int i = 0; i < 4; i++)
                            acc[i][j][g] = __builtin_amdgcn_mfma_f32_16x16x32_bf16(a[i], b, acc[i][j][g], 0, 0, 0);
                    }
                }
            }
        }
    }
    // LSTM epilogue -> LDS
#pragma unroll
    for (int j = 0; j < 2; j++) {
        int cc = half * 8 + wv * 2 + j;
        int c = cc * 16 + lm;                        // global channel 0..255
        int cl = (wv * 2 + j) * 16 + lm;             // local 0..127
        float bi_ = bl[c], bo_ = bl[512 + c], bg_ = bl[768 + c];
#pragma unroll
        for (int i = 0; i < 4; i++) {
#pragma unroll
            for (int r = 0; r < 4; r++) {
                int b_in = i * 16 + q * 4 + r;
                float m = m2h[hw * 2048 + b0 + b_in];
                float val = 0.f;
                if (m > 0.f) {
                    float iv = acc[i][j][0][r] + bi_;
                    float ov = acc[i][j][1][r] + bo_;
                    float gv = acc[i][j][2][r] + bg_;
                    float ct = sigmoidf_(iv) * tanhf_(gv);
                    val = sigmoidf_(ov) * tanhf_(ct);
                }
                sm[b_in][cl] = f2b(val);
            }
        }
    }
    __syncthreads();
    // coalesced copy LDS -> goutT8: 1024 x 16B entries; entry e: c8l = e>>6, b_in = e&63
#pragma unroll
    for (int k = 0; k < 4; k++) {
        int e = k * 256 + tid;
        int c8l = e >> 6, b_in = e & 63;
        union { uint4 u; bf16 h8[8]; } v;
#pragma unroll
        for (int i = 0; i < 8; i++) v.h8[i] = sm[b_in][c8l * 8 + i];
        long dst = ((long)(hw * 32 + half * 16 + c8l)) * 2048 + b0 + b_in;
        *(uint4*)(goutT8 + dst * 8) = v.u;
    }
}

// ---------------- FC1 via MFMA, T8 layouts (fully coalesced fragment loads) ----------------
__global__ void fc1_mfma(const bf16* __restrict__ AT8, const bf16* __restrict__ WT8,
                         const float* __restrict__ lb1, bf16* __restrict__ y1) {
    const int tid = threadIdx.x;
    const int wv = tid >> 6;
    const int L  = tid & 63;
    const int q  = L >> 4, lm = L & 15;
    const int wm = wv >> 1, wn = wv & 1;
    const int bm = blockIdx.x & 31;
    const int bn = blockIdx.x >> 5;
    const int m0 = bm * 64 + wm * 32;
    const int n0 = bn * 64 + wn * 32;

    f4v acc[2][2];
#pragma unroll
    for (int i = 0; i < 2; i++)
#pragma unroll
        for (int j = 0; j < 2; j++) acc[i][j] = (f4v){0.f, 0.f, 0.f, 0.f};

#pragma unroll 2
    for (int k8 = 0; k8 < 1120; k8 += 4) {
        long ar = ((long)(k8 + q)) * 2048;
        long br = ((long)(k8 + q)) * 1024;
        s8v a0 = *(const s8v*)(AT8 + (ar + m0 + lm) * 8);
        s8v a1 = *(const s8v*)(AT8 + (ar + m0 + 16 + lm) * 8);
        s8v b0 = *(const s8v*)(WT8 + (br + n0 + lm) * 8);
        s8v b1 = *(const s8v*)(WT8 + (br + n0 + 16 + lm) * 8);
        acc[0][0] = __builtin_amdgcn_mfma_f32_16x16x32_bf16(a0, b0, acc[0][0], 0, 0, 0);
        acc[0][1] = __builtin_amdgcn_mfma_f32_16x16x32_bf16(a0, b1, acc[0][1], 0, 0, 0);
        acc[1][0] = __builtin_amdgcn_mfma_f32_16x16x32_bf16(a1, b0, acc[1][0], 0, 0, 0);
        acc[1][1] = __builtin_amdgcn_mfma_f32_16x16x32_bf16(a1, b1, acc[1][1], 0, 0, 0);
    }
#pragma unroll
    for (int i = 0; i < 2; i++) {
#pragma unroll
        for (int j = 0; j < 2; j++) {
            int nn = n0 + j * 16 + lm;
            float bias = lb1[nn];
#pragma unroll
            for (int r = 0; r < 4; r++) {
                int mm = m0 + i * 16 + q * 4 + r;
                y1[(long)mm * 1024 + nn] = f2b(fmaxf(acc[i][j][r] + bias, 0.f));
            }
        }
    }
}

// ---------------- FC2 via MFMA: y1[2048,1024] x (whi+wlo)[1024,448] + lb2 -> out[2048,420] ----------------
__global__ void fc2_mfma(const bf16* __restrict__ y1, const bf16* __restrict__ whi,
                         const bf16* __restrict__ wlo, const float* __restrict__ lb2,
                         float* __restrict__ out) {
    const int tid = threadIdx.x;
    const int wv = tid >> 6;
    const int L  = tid & 63;
    const int q  = L >> 4, lm = L & 15;
    const int wm = wv >> 1, wn = wv & 1;
    const int bm = blockIdx.x % 32;
    const int bn = blockIdx.x / 32;
    const int m0 = bm * 64 + wm * 32;
    const int n0 = bn * 64 + wn * 32;

    f4v acc[2][2];
#pragma unroll
    for (int i = 0; i < 2; i++)
#pragma unroll
        for (int j = 0; j < 2; j++) acc[i][j] = (f4v){0.f, 0.f, 0.f, 0.f};

#pragma unroll 2
    for (int k8 = 0; k8 < 128; k8 += 4) {
        const bf16* arow = y1 + (long)(k8 + q) * 8;
        long br = ((long)(k8 + q)) * 448;
        s8v a0 = *(const s8v*)(arow + (long)(m0 + lm) * 1024);
        s8v a1 = *(const s8v*)(arow + (long)(m0 + 16 + lm) * 1024);
        s8v h0 = *(const s8v*)(whi + (br + n0 + lm) * 8);
        s8v h1 = *(const s8v*)(whi + (br + n0 + 16 + lm) * 8);
        s8v l0 = *(const s8v*)(wlo + (br + n0 + lm) * 8);
        s8v l1 = *(const s8v*)(wlo + (br + n0 + 16 + lm) * 8);
        acc[0][0] = __builtin_amdgcn_mfma_f32_16x16x32_bf16(a0, h0, acc[0][0], 0, 0, 0);
        acc[0][1] = __builtin_amdgcn_mfma_f32_16x16x32_bf16(a0, h1, acc[0][1], 0, 0, 0);
        acc[1][0] = __builtin_amdgcn_mfma_f32_16x16x32_bf16(a1, h0, acc[1][0], 0, 0, 0);
        acc[1][1] = __builtin_amdgcn_mfma_f32_16x16x32_bf16(a1, h1, acc[1][1], 0, 0, 0);
        acc[0][0] = __builtin_amdgcn_mfma_f32_16x16x32_bf16(a0, l0, acc[0][0], 0, 0, 0);
        acc[0][1] = __builtin_amdgcn_mfma_f32_16x16x32_bf16(a0, l1, acc[0][1], 0, 0, 0);
        acc[1][0] = __builtin_amdgcn_mfma_f32_16x16x32_bf16(a1, l0, acc[1][0], 0, 0, 0);
        acc[1][1] = __builtin_amdgcn_mfma_f32_16x16x32_bf16(a1, l1, acc[1][1], 0, 0, 0);
    }
#pragma unroll
    for (int j = 0; j < 2; j++) {
        int nn = n0 + j * 16 + lm;
        if (nn >= 420) continue;
        float bias = lb2[nn];
#pragma unroll
        for (int i = 0; i < 2; i++) {
#pragma unroll
            for (int r = 0; r < 4; r++) {
                int mm = m0 + i * 16 + q * 4 + r;
                out[(long)mm * 420 + nn] = acc[i][j][r] + bias;
            }
        }
    }
}

// ---------------- launch ----------------
extern "C" void kernel_launch(void* const* d_in, const int* in_sizes, int n_in,
                              void* d_out, int out_size, void* d_ws, size_t ws_size,
                              hipStream_t stream) {
    const float* x    = (const float*)d_in[0];
    const int*   mask = (const int*)d_in[1];
    const float* W1 = (const float*)d_in[2];
    const float* g1 = (const float*)d_in[3];
    const float* b1 = (const float*)d_in[4];
    const float* W2 = (const float*)d_in[5];
    const float* g2 = (const float*)d_in[6];
    const float* b2 = (const float*)d_in[7];
    const float* W3 = (const float*)d_in[8];
    const float* g3 = (const float*)d_in[9];
    const float* b3 = (const float*)d_in[10];
    const float* W4 = (const float*)d_in[11];
    const float* g4 = (const float*)d_in[12];
    const float* b4 = (const float*)d_in[13];
    const float* Wl = (const float*)d_in[14];
    const float* bl = (const float*)d_in[15];
    const float* lw1 = (const float*)d_in[16];
    const float* lb1 = (const float*)d_in[17];
    const float* lw2 = (const float*)d_in[18];
    const float* lb2 = (const float*)d_in[19];
    float* out = (float*)d_out;

    float* ws = (float*)d_ws;
    float* m0 = ws + OFF_M0;
    float* m1 = ws + OFF_M1;
    float* m2h = ws + OFF_M2;
    bf16* bufA = (bf16*)(ws + OFF_BF);
    bf16* bufB = bufA + SZ_A;

    bf16* c1     = bufA;          // [NSITE1,16]
    bf16* xm     = bufB;          // [NSITE1,2]
    bf16* c2     = bufB;          // [NSITE1,32]
    bf16* p1     = bufA;          // [NSITE2,32]
    bf16* c3     = bufB;          // [NSITE2,64]
    bf16* c4     = bufA;          // [NSITE2,128]
    bf16* p2T8   = bufB;          // [16][35][2048][8]
    bf16* goutT8 = bufA;          // [1120][2048][8]
    bf16* y1     = bufB;          // [2048,1024]
    bf16* wb2    = bufA + WB2_A;
    bf16* wb3    = bufB + WB3_B;
    bf16* wb4    = bufB + WB4_B;
    bf16* wbl3   = bufA + WBL_A;
    bf16* wfc1   = bufB + WFC1_B;
    bf16* wfc2h  = bufB + WFC2_B;           // [128][448][8]
    bf16* wfc2l  = wfc2h + 458752;

    // f32 stat buckets in dead regions (see lifetime notes at the BKT_* constants)
    float* bkt16  = (float*)(bufA + BKT_A);            //  64*2*16  = 2048 f
    float* bkt32  = bkt16 + 2048;                      //  64*2*32  = 4096 f
    float* bkt64  = (float*)(bufB + BKT_B);            //  64*2*64  = 8192 f
    float* bkt128 = bkt64 + 8192;                      //  64*2*128 = 16384 f

    hipMemsetAsync(ws, 0, 4096, stream);               // BN counts
    hipMemsetAsync(bkt16, 0, (2048 + 4096) * 4, stream);

    // prep + W2 cvt merged (5704 + 36 blocks)
    prep_cvtw2_k<<<5740, 256, 0, stream>>>(x, mask, m0, xm, W2, wb2);

    // conv1 with fused BN1-stats (shuffle-reduced) + N1 count
    conv1_k<<<5704, 256, 0, stream>>>(xm, W1, m0, c1, bkt16, ws + OFF_N1);

    // conv2: in-block BN1 fold + staged apply + fused BN2-stats
    conv_mfma<16, 32, 32, 1, 2, 1, IH, IW, true, true, true, false>
        <<<(int)(NSITE1 / 64), 256, 0, stream>>>(c1, wb2, m0,
                                                 bkt16, ws + OFF_N1, g1, b1,
                                                 c2, bkt32, nullptr);

    // pool1: in-block BN2 fold + affine/relu
    maxpool_bn<32><<<(int)(NSITE2 * 32 / 8 / 256), 256, 0, stream>>>(
        c2, m0, bkt32, ws + OFF_N1, g2, b2, p1, m1, BB, IH, IW, PH, PW);

    // c2 (bufB) dead: zero bkt64+bkt128, then merged weight converts into bufB slack
    hipMemsetAsync(bkt64, 0, (8192 + 16384) * 4, stream);
    cvt_all_k<<<5064, 256, 0, stream>>>(W3, W4, lw1, lw2, wb3, wb4, wfc1, wfc2h, wfc2l);

    // conv3: input already BN'd by pool; fused BN3-stats + N2 count
    conv_mfma<32, 32, 64, 1, 4, 1, PH, PW, false, false, true, true>
        <<<(int)(NSITE2 / 64), 256, 0, stream>>>(p1, wb3, m1,
                                                 nullptr, nullptr, nullptr, nullptr,
                                                 c3, bkt64, ws + OFF_N2);

    // conv4: in-block BN3 fold + staged apply + fused BN4-stats
    conv_mfma<64, 64, 128, 2, 4, 2, PH, PW, false, true, true, false>
        <<<(int)(NSITE2 / 64), 256, 0, stream>>>(c3, wb4, m1,
                                                 bkt64, ws + OFF_N2, g3, b3,
                                                 c4, bkt128, nullptr);

    // pool2: in-block BN4 fold -> p2T8 + m2h
    maxpool_p2t<<<4480, 256, 0, stream>>>(c4, m1, bkt128, ws + OFF_N2, g4, b4, p2T8, m2h);

    // c4 (bufA) dead: convert wbl3 into bufA past goutT8's end
    cvt_wl3_k<<<(884736 + 255) / 256, 256, 0, stream>>>(Wl, wbl3);

    gates_mfma<<<2240, 256, 0, stream>>>(p2T8, wbl3, bl, m2h, goutT8);

    fc1_mfma<<<512, 256, 0, stream>>>(goutT8, wfc1, lb1, y1);

    fc2_mfma<<<224, 256, 0, stream>>>(y1, wfc2h, wfc2l, lb2, out);
}